// Round 20
// baseline (28.005 us; speedup 1.0000x reference)
//
#include <hip/hip_runtime.h>
#include <math.h>

#define HDIM 512
#define WDIM 512
#define SEG 16        // segments per column (vert pass)
#define SROWS 32      // rows per segment (SEG * SROWS == HDIM)
#define VCOLS 32      // columns per block (vert pass)
#define VTHREADS 512  // VCOLS * SEG
#define ROWS_PB 4     // rows per tile (horiz pass)
#define HTHREADS 256
#define TILES_PB 2    // tiles per block (r16/r19 verified geometry)
#define PAD 16        // envelope pad each side (supports rad<=8 clamp-free)
#define LROW (WDIM + 2 * PAD)   // 544 floats
#define INF_I (1 << 20)
#define ENC_SENT 127  // int8 clamp; |sv|==127 encodes the 1e6 sentinel

// ws layout: [256..256+8*npart): partial doubles
//            [16384..16384+4*2048): warm-read sink floats (never read back)
//            [32768..): sdist (int8, N)

// ---------------- pass 1: vertical EDT -> signed int8, + outp L3-warm ----------------
// r12 evidence: horiz runs 9.45us warm vs ~20us cold. Vert streams only 20MB
// and leaves BW idle, so it additionally touches all of outp (16MB, float4
// loads) to pull it into L3 before horiz launches. Loads are kept live via a
// wave-reduce into a dummy ws sink (deterministic; never read by finalize).
__global__ __launch_bounds__(VTHREADS) void vert_pass19(const int* __restrict__ tgt,
                                                        signed char* __restrict__ sdist,
                                                        const float* __restrict__ outp,
                                                        float* __restrict__ sink) {
    __shared__ int s_fs1[SEG][VCOLS], s_ls1[SEG][VCOLS];
    __shared__ int s_fs0[SEG][VCOLS], s_ls0[SEG][VCOLS];
    __shared__ int s_c1f[SEG][VCOLS], s_c1b[SEG][VCOLS];
    __shared__ int s_c0f[SEG][VCOLS], s_c0b[SEG][VCOLS];

    int tid = threadIdx.x;
    int w = tid & (VCOLS - 1);
    int seg = tid >> 5;
    int bW = WDIM / VCOLS;
    int b = blockIdx.x / bW;
    int wbase = (blockIdx.x % bW) * VCOLS;
    size_t colbase = (size_t)b * HDIM * WDIM + wbase + w;
    const int* col = tgt + colbase + (size_t)(seg * SROWS) * WDIM;

    unsigned R1 = 0u;
    #pragma unroll 8
    for (int h = 0; h < SROWS; ++h) {
        int tv = col[(size_t)h * WDIM];
        R1 |= ((unsigned)(tv != 0)) << h;
    }
    unsigned R0 = ~R1;

    // issue outp warm loads early: latency hides under carry-chain + store work
    const float4* op4 = (const float4*)outp;
    size_t wt0 = ((size_t)blockIdx.x * VTHREADS + tid) * 8;   // exact cover of N/4
    float4 wv[8];
    #pragma unroll
    for (int i = 0; i < 8; ++i) wv[i] = op4[wt0 + i];

    s_fs1[seg][w] = R1 ? __builtin_ctz(R1) : SROWS;
    s_ls1[seg][w] = R1 ? 31 - __builtin_clz(R1) : -1;
    s_fs0[seg][w] = R0 ? __builtin_ctz(R0) : SROWS;
    s_ls0[seg][w] = R0 ? 31 - __builtin_clz(R0) : -1;
    __syncthreads();

    if (tid < 128) {
        int cw = tid & (VCOLS - 1);
        int md = tid >> 5;
        int c = INF_I;
        if (md == 0) {
            for (int s = 0; s < SEG; ++s) {
                s_c1f[s][cw] = c;
                int ls = s_ls1[s][cw];
                c = (ls >= 0) ? (SROWS - 1 - ls) : c + SROWS;
            }
        } else if (md == 1) {
            for (int s = SEG - 1; s >= 0; --s) {
                s_c1b[s][cw] = c;
                int fs = s_fs1[s][cw];
                c = (fs < SROWS) ? fs : c + SROWS;
            }
        } else if (md == 2) {
            for (int s = 0; s < SEG; ++s) {
                s_c0f[s][cw] = c;
                int ls = s_ls0[s][cw];
                c = (ls >= 0) ? (SROWS - 1 - ls) : c + SROWS;
            }
        } else {
            for (int s = SEG - 1; s >= 0; --s) {
                s_c0b[s][cw] = c;
                int fs = s_fs0[s][cw];
                c = (fs < SROWS) ? fs : c + SROWS;
            }
        }
    }
    __syncthreads();

    int c1f = s_c1f[seg][w], c1b = s_c1b[seg][w];
    int c0f = s_c0f[seg][w], c0b = s_c0b[seg][w];

    signed char* os = sdist + colbase + (size_t)(seg * SROWS) * WDIM;

    unsigned mle = 0u;
    for (int h = 0; h < SROWS; ++h) {
        mle = (mle << 1) | 1u;
        unsigned a1 = R1 & mle;
        int d1f = a1 ? (h - (31 - __builtin_clz(a1))) : c1f + h + 1;
        unsigned b1 = R1 >> h;
        int d1b = b1 ? __builtin_ctz(b1) : c1b + (SROWS - h);
        int g1 = min(d1f, d1b);
        unsigned a0 = R0 & mle;
        int d0f = a0 ? (h - (31 - __builtin_clz(a0))) : c0f + h + 1;
        unsigned b0 = R0 >> h;
        int d0b = b0 ? __builtin_ctz(b0) : c0b + (SROWS - h);
        int g0 = min(d0f, d0b);

        signed char sval = ((R1 >> h) & 1u) ? (signed char)(-min(g0, ENC_SENT))
                                            : (signed char)min(g1, ENC_SENT);
        os[(size_t)h * WDIM] = sval;
    }

    // keep warm loads live: wave-reduce, one store per wave to dummy sink
    float acc = 0.0f;
    #pragma unroll
    for (int i = 0; i < 8; ++i) acc += wv[i].x + wv[i].y + wv[i].z + wv[i].w;
    #pragma unroll
    for (int off = 32; off > 0; off >>= 1) acc += __shfl_down(acc, off, 64);
    if ((tid & 63) == 0) sink[blockIdx.x * (VTHREADS / 64) + (tid >> 6)] = acc;
}

// ---- decode one packed-int8 quad into both LDS envelopes (verified) ----
__device__ __forceinline__ void stage_write(float* sf1, float* sf0, int p, int qidx) {
    int j = qidx * 4;
    int row = j >> 9;
    int lbase = row * LROW + PAD + (j & (WDIM - 1));
    float4 q1, q0;
    float* q1f = (float*)&q1;
    float* q0f = (float*)&q0;
    #pragma unroll
    for (int k = 0; k < 4; ++k) {
        int sv = (p << (24 - 8 * k)) >> 24;
        int e2 = sv * sv;
        float f = (float)e2;
        f = (e2 == ENC_SENT * ENC_SENT) ? 1.0e12f : f;
        bool neg = sv < 0;
        q1f[k] = neg ? 0.0f : f;
        q0f[k] = neg ? f : 0.0f;
    }
    *(float4*)(sf1 + lbase) = q1;
    *(float4*)(sf0 + lbase) = q0;
}

// ---- scan one quad (verified body) ----
__device__ __forceinline__ float scan_quad(const float* sf1, const float* sf0,
                                           int idx0, float4 xq) {
    int row = idx0 >> 9;
    int j0 = idx0 & (WDIM - 1);
    int wb = row * LROW + PAD + j0;

    float w1[16], w0[16];
    *(float4*)(w1 + 0)  = *(const float4*)(sf1 + wb - 8);
    *(float4*)(w1 + 4)  = *(const float4*)(sf1 + wb - 4);
    *(float4*)(w1 + 8)  = *(const float4*)(sf1 + wb + 0);
    *(float4*)(w1 + 12) = *(const float4*)(sf1 + wb + 4);
    *(float4*)(w0 + 0)  = *(const float4*)(sf0 + wb - 8);
    *(float4*)(w0 + 4)  = *(const float4*)(sf0 + wb - 4);
    *(float4*)(w0 + 8)  = *(const float4*)(sf0 + wb + 0);
    *(float4*)(w0 + 12) = *(const float4*)(sf0 + wb + 4);

    float best[4];
    bool cls[4];
    #pragma unroll
    for (int q = 0; q < 4; ++q) {
        bool c0 = w1[8 + q] > 0.0f;
        cls[q] = c0;
        float b = c0 ? w1[8 + q] : w0[8 + q];
        #pragma unroll
        for (int rad = 1; rad <= 4; ++rad) {
            float rr = (float)(rad * rad);
            float cl = c0 ? w1[8 + q - rad] : w0[8 + q - rad];
            float cr = c0 ? w1[8 + q + rad] : w0[8 + q + rad];
            b = fminf(b, rr + fminf(cl, cr));
        }
        best[q] = b;
    }

    float qmax = fmaxf(fmaxf(best[0], best[1]), fmaxf(best[2], best[3]));
    if (qmax > 25.0f) {
        float e1[4], e0[4];
        *(float4*)e1 = *(const float4*)(sf1 + wb + 8);
        *(float4*)e0 = *(const float4*)(sf0 + wb + 8);
        #pragma unroll
        for (int q = 0; q < 4; ++q) {
            bool c0 = cls[q];
            float b = best[q];
            #pragma unroll
            for (int rad = 5; rad <= 8; ++rad) {
                float rr = (float)(rad * rad);
                int li = 8 + q - rad;
                int ri = 8 + q + rad;
                float cl = c0 ? w1[li] : w0[li];
                float cr = (ri < 16) ? (c0 ? w1[ri] : w0[ri])
                                     : (c0 ? e1[ri - 16] : e0[ri - 16]);
                b = fminf(b, rr + fminf(cl, cr));
            }
            best[q] = b;
        }
        #pragma unroll
        for (int q = 0; q < 4; ++q) {
            if (best[q] > 81.0f) {
                int j = j0 + q;
                const float* env = (cls[q] ? sf1 : sf0) + row * LROW + PAD;
                float b = best[q];
                float rr = 81.0f;
                for (int rad = 9; rad < WDIM; ++rad) {
                    if (rr >= b) break;
                    int kl = j - rad; kl = kl < 0 ? 0 : kl;
                    int kr = j + rad; kr = kr > WDIM - 1 ? WDIM - 1 : kr;
                    b = fminf(b, fminf(rr + env[kl], rr + env[kr]));
                    rr += 2.0f * (float)rad + 1.0f;
                }
                best[q] = b;
            }
        }
    }

    const float* xs = (const float*)&xq;
    float s = 0.0f;
    #pragma unroll
    for (int q = 0; q < 4; ++q) {
        float sd = __builtin_amdgcn_sqrtf(best[q]);
        float dist = cls[q] ? sd : -sd;
        float prob = __fdividef(1.0f, 1.0f + __expf(-xs[q]));
        s += prob * dist;
    }
    return s;
}

// ---------------- pass 2: 2-tile pipelined horiz (r19 verified, unchanged) ----------------
__global__ __launch_bounds__(HTHREADS) void horiz_pass19(const int* __restrict__ sdist4,
                                                         const float* __restrict__ outp,
                                                         double* __restrict__ partial) {
    __shared__ float sf1[ROWS_PB * LROW];
    __shared__ float sf0[ROWS_PB * LROW];
    __shared__ double swave[4];

    int tid = threadIdx.x;
    size_t base0 = (size_t)(blockIdx.x * TILES_PB + 0) * (ROWS_PB * WDIM);
    size_t base1 = (size_t)(blockIdx.x * TILES_PB + 1) * (ROWS_PB * WDIM);

    int pa0 = sdist4[base0 / 4 + tid];
    int pa1 = sdist4[base0 / 4 + HTHREADS + tid];
    int pb0 = sdist4[base1 / 4 + tid];
    int pb1 = sdist4[base1 / 4 + HTHREADS + tid];
    float4 xa0 = *(const float4*)(outp + base0 + tid * 4);
    float4 xa1 = *(const float4*)(outp + base0 + (size_t)(HTHREADS + tid) * 4);
    float4 xb0 = *(const float4*)(outp + base1 + tid * 4);
    float4 xb1 = *(const float4*)(outp + base1 + (size_t)(HTHREADS + tid) * 4);

    if (tid < ROWS_PB * 2 * PAD) {
        int r = tid / (2 * PAD);
        int c = tid % (2 * PAD);
        int off = r * LROW + (c < PAD ? c : WDIM + c);
        sf1[off] = 3.0e12f;
        sf0[off] = 3.0e12f;
    }

    stage_write(sf1, sf0, pa0, tid);
    stage_write(sf1, sf0, pa1, HTHREADS + tid);
    __syncthreads();

    float local = 0.0f;
    local += scan_quad(sf1, sf0, tid * 4, xa0);
    local += scan_quad(sf1, sf0, (HTHREADS + tid) * 4, xa1);
    __syncthreads();

    stage_write(sf1, sf0, pb0, tid);
    stage_write(sf1, sf0, pb1, HTHREADS + tid);
    __syncthreads();

    local += scan_quad(sf1, sf0, tid * 4, xb0);
    local += scan_quad(sf1, sf0, (HTHREADS + tid) * 4, xb1);

    float v = local;
    #pragma unroll
    for (int off = 32; off > 0; off >>= 1) v += __shfl_down(v, off, 64);
    int wid = tid >> 6, lane = tid & 63;
    if (lane == 0) swave[wid] = (double)v;
    __syncthreads();
    if (tid == 0) partial[blockIdx.x] = swave[0] + swave[1] + swave[2] + swave[3];
}

// ---------------- finalize: sum partials -> mean ----------------
__global__ __launch_bounds__(256) void finalize19(const double* __restrict__ partial,
                                                  float* __restrict__ out,
                                                  int npart, double invN) {
    __shared__ double swave[4];
    int tid = threadIdx.x;
    double local = 0.0;
    for (int i = tid; i < npart; i += 256) local += partial[i];
    #pragma unroll
    for (int off = 32; off > 0; off >>= 1) local += __shfl_down(local, off, 64);
    int wid = tid >> 6, lane = tid & 63;
    if (lane == 0) swave[wid] = local;
    __syncthreads();
    if (tid == 0) out[0] = (float)((swave[0] + swave[1] + swave[2] + swave[3]) * invN);
}

extern "C" void kernel_launch(void* const* d_in, const int* in_sizes, int n_in,
                              void* d_out, int out_size, void* d_ws, size_t ws_size,
                              hipStream_t stream) {
    const float* outp = (const float*)d_in[0];
    const int* tgt = (const int*)d_in[1];
    int N = in_sizes[0];                    // B*C*H*W
    int B = N / (HDIM * WDIM);              // 16

    int npart = (B * HDIM) / (ROWS_PB * TILES_PB);   // 1024

    double* partial = (double*)((char*)d_ws + 256);
    float* sink = (float*)((char*)d_ws + 16384);
    signed char* sdist = (signed char*)((char*)d_ws + 32768);

    vert_pass19<<<B * (WDIM / VCOLS), VTHREADS, 0, stream>>>(tgt, sdist, outp, sink);
    horiz_pass19<<<npart, HTHREADS, 0, stream>>>((const int*)sdist, outp, partial);
    finalize19<<<1, 256, 0, stream>>>(partial, (float*)d_out, npart, 1.0 / (double)N);
}

// Round 21
// 25.601 us; speedup vs baseline: 1.0939x; 1.0939x over previous
//
#include <hip/hip_runtime.h>
#include <math.h>

#define HDIM 512
#define WDIM 512
#define SEG 16        // segments per column (vert pass)
#define SROWS 32      // rows per segment (SEG * SROWS == HDIM)
#define VCOLS 32      // columns per block (vert pass)
#define VTHREADS 512  // VCOLS * SEG
#define ROWS_PB 4     // rows per tile (horiz pass)
#define HTHREADS 256
#define TILES_PB 2    // tiles per block (depth-1 register prefetch pipeline)
#define PAD 16        // envelope pad each side (supports rad<=8 clamp-free)
#define LROW (WDIM + 2 * PAD)   // 544 floats
#define INF_I (1 << 20)
#define ENC_SENT 127  // int8 clamp; |sv|==127 encodes the 1e6 sentinel

// ws layout: [256..256+8*npart): partial doubles | [32768..): sdist (int8, N)

// ---------------- pass 1: vertical 1D EDT -> signed int8 (verified) ----------------
__global__ __launch_bounds__(VTHREADS) void vert_pass20(const int* __restrict__ tgt,
                                                        signed char* __restrict__ sdist) {
    __shared__ int s_fs1[SEG][VCOLS], s_ls1[SEG][VCOLS];
    __shared__ int s_fs0[SEG][VCOLS], s_ls0[SEG][VCOLS];
    __shared__ int s_c1f[SEG][VCOLS], s_c1b[SEG][VCOLS];
    __shared__ int s_c0f[SEG][VCOLS], s_c0b[SEG][VCOLS];

    int tid = threadIdx.x;
    int w = tid & (VCOLS - 1);
    int seg = tid >> 5;
    int bW = WDIM / VCOLS;
    int b = blockIdx.x / bW;
    int wbase = (blockIdx.x % bW) * VCOLS;
    size_t colbase = (size_t)b * HDIM * WDIM + wbase + w;
    const int* col = tgt + colbase + (size_t)(seg * SROWS) * WDIM;

    unsigned R1 = 0u;
    #pragma unroll 8
    for (int h = 0; h < SROWS; ++h) {
        int tv = col[(size_t)h * WDIM];
        R1 |= ((unsigned)(tv != 0)) << h;
    }
    unsigned R0 = ~R1;

    s_fs1[seg][w] = R1 ? __builtin_ctz(R1) : SROWS;
    s_ls1[seg][w] = R1 ? 31 - __builtin_clz(R1) : -1;
    s_fs0[seg][w] = R0 ? __builtin_ctz(R0) : SROWS;
    s_ls0[seg][w] = R0 ? 31 - __builtin_clz(R0) : -1;
    __syncthreads();

    if (tid < 128) {
        int cw = tid & (VCOLS - 1);
        int md = tid >> 5;
        int c = INF_I;
        if (md == 0) {
            for (int s = 0; s < SEG; ++s) {
                s_c1f[s][cw] = c;
                int ls = s_ls1[s][cw];
                c = (ls >= 0) ? (SROWS - 1 - ls) : c + SROWS;
            }
        } else if (md == 1) {
            for (int s = SEG - 1; s >= 0; --s) {
                s_c1b[s][cw] = c;
                int fs = s_fs1[s][cw];
                c = (fs < SROWS) ? fs : c + SROWS;
            }
        } else if (md == 2) {
            for (int s = 0; s < SEG; ++s) {
                s_c0f[s][cw] = c;
                int ls = s_ls0[s][cw];
                c = (ls >= 0) ? (SROWS - 1 - ls) : c + SROWS;
            }
        } else {
            for (int s = SEG - 1; s >= 0; --s) {
                s_c0b[s][cw] = c;
                int fs = s_fs0[s][cw];
                c = (fs < SROWS) ? fs : c + SROWS;
            }
        }
    }
    __syncthreads();

    int c1f = s_c1f[seg][w], c1b = s_c1b[seg][w];
    int c0f = s_c0f[seg][w], c0b = s_c0b[seg][w];

    signed char* os = sdist + colbase + (size_t)(seg * SROWS) * WDIM;

    unsigned mle = 0u;
    for (int h = 0; h < SROWS; ++h) {
        mle = (mle << 1) | 1u;
        unsigned a1 = R1 & mle;
        int d1f = a1 ? (h - (31 - __builtin_clz(a1))) : c1f + h + 1;
        unsigned b1 = R1 >> h;
        int d1b = b1 ? __builtin_ctz(b1) : c1b + (SROWS - h);
        int g1 = min(d1f, d1b);
        unsigned a0 = R0 & mle;
        int d0f = a0 ? (h - (31 - __builtin_clz(a0))) : c0f + h + 1;
        unsigned b0 = R0 >> h;
        int d0b = b0 ? __builtin_ctz(b0) : c0b + (SROWS - h);
        int g0 = min(d0f, d0b);

        signed char sval = ((R1 >> h) & 1u) ? (signed char)(-min(g0, ENC_SENT))
                                            : (signed char)min(g1, ENC_SENT);
        os[(size_t)h * WDIM] = sval;
    }
}

// ---- decode one packed-int8 quad into both LDS envelopes (verified) ----
__device__ __forceinline__ void stage_write(float* sf1, float* sf0, int p, int qidx) {
    int j = qidx * 4;                       // pixel index within tile [0, 2048)
    int row = j >> 9;
    int lbase = row * LROW + PAD + (j & (WDIM - 1));
    float4 q1, q0;
    float* q1f = (float*)&q1;
    float* q0f = (float*)&q0;
    #pragma unroll
    for (int k = 0; k < 4; ++k) {
        int sv = (p << (24 - 8 * k)) >> 24;
        int e2 = sv * sv;
        float f = (float)e2;
        f = (e2 == ENC_SENT * ENC_SENT) ? 1.0e12f : f;
        bool neg = sv < 0;
        q1f[k] = neg ? 0.0f : f;
        q0f[k] = neg ? f : 0.0f;
    }
    *(float4*)(sf1 + lbase) = q1;
    *(float4*)(sf0 + lbase) = q0;
}

// ---- scan one quad (verified body) ----
__device__ __forceinline__ float scan_quad(const float* sf1, const float* sf0,
                                           int idx0, float4 xq) {
    int row = idx0 >> 9;
    int j0 = idx0 & (WDIM - 1);
    int wb = row * LROW + PAD + j0;

    float w1[16], w0[16];
    *(float4*)(w1 + 0)  = *(const float4*)(sf1 + wb - 8);
    *(float4*)(w1 + 4)  = *(const float4*)(sf1 + wb - 4);
    *(float4*)(w1 + 8)  = *(const float4*)(sf1 + wb + 0);
    *(float4*)(w1 + 12) = *(const float4*)(sf1 + wb + 4);
    *(float4*)(w0 + 0)  = *(const float4*)(sf0 + wb - 8);
    *(float4*)(w0 + 4)  = *(const float4*)(sf0 + wb - 4);
    *(float4*)(w0 + 8)  = *(const float4*)(sf0 + wb + 0);
    *(float4*)(w0 + 12) = *(const float4*)(sf0 + wb + 4);

    float best[4];
    bool cls[4];
    #pragma unroll
    for (int q = 0; q < 4; ++q) {
        bool c0 = w1[8 + q] > 0.0f;         // f1[j]>0 <=> tgt==0 pixel
        cls[q] = c0;
        float b = c0 ? w1[8 + q] : w0[8 + q];
        #pragma unroll
        for (int rad = 1; rad <= 4; ++rad) {
            float rr = (float)(rad * rad);
            float cl = c0 ? w1[8 + q - rad] : w0[8 + q - rad];
            float cr = c0 ? w1[8 + q + rad] : w0[8 + q + rad];
            b = fminf(b, rr + fminf(cl, cr));
        }
        best[q] = b;
    }

    float qmax = fmaxf(fmaxf(best[0], best[1]), fmaxf(best[2], best[3]));
    if (qmax > 25.0f) {
        float e1[4], e0[4];
        *(float4*)e1 = *(const float4*)(sf1 + wb + 8);
        *(float4*)e0 = *(const float4*)(sf0 + wb + 8);
        #pragma unroll
        for (int q = 0; q < 4; ++q) {
            bool c0 = cls[q];
            float b = best[q];
            #pragma unroll
            for (int rad = 5; rad <= 8; ++rad) {
                float rr = (float)(rad * rad);
                int li = 8 + q - rad;
                int ri = 8 + q + rad;
                float cl = c0 ? w1[li] : w0[li];
                float cr = (ri < 16) ? (c0 ? w1[ri] : w0[ri])
                                     : (c0 ? e1[ri - 16] : e0[ri - 16]);
                b = fminf(b, rr + fminf(cl, cr));
            }
            best[q] = b;
        }
        #pragma unroll
        for (int q = 0; q < 4; ++q) {
            if (best[q] > 81.0f) {
                int j = j0 + q;
                const float* env = (cls[q] ? sf1 : sf0) + row * LROW + PAD;
                float b = best[q];
                float rr = 81.0f;
                for (int rad = 9; rad < WDIM; ++rad) {
                    if (rr >= b) break;
                    int kl = j - rad; kl = kl < 0 ? 0 : kl;
                    int kr = j + rad; kr = kr > WDIM - 1 ? WDIM - 1 : kr;
                    b = fminf(b, fminf(rr + env[kl], rr + env[kr]));
                    rr += 2.0f * (float)rad + 1.0f;
                }
                best[q] = b;
            }
        }
    }

    const float* xs = (const float*)&xq;
    float s = 0.0f;
    #pragma unroll
    for (int q = 0; q < 4; ++q) {
        float sd = __builtin_amdgcn_sqrtf(best[q]);
        float dist = cls[q] ? sd : -sd;
        float prob = __fdividef(1.0f, 1.0f + __expf(-xs[q]));
        s += prob * dist;
    }
    return s;
}

// ---------------- pass 2: 2-tile pipelined horiz (round-16 verified optimum) ----------------
// stage tile0 -> barrier -> [issue tile1 loads; scan tile0] -> barrier ->
// stage tile1 -> barrier -> scan tile1. Tile1's load latency hides under
// tile0's scan. 1024 blocks (4/CU), single 17.4KB LDS buffer pair.
__global__ __launch_bounds__(HTHREADS) void horiz_pass20(const int* __restrict__ sdist4,
                                                         const float* __restrict__ outp,
                                                         double* __restrict__ partial) {
    __shared__ float sf1[ROWS_PB * LROW];
    __shared__ float sf0[ROWS_PB * LROW];
    __shared__ double swave[4];

    int tid = threadIdx.x;
    size_t base0 = (size_t)(blockIdx.x * TILES_PB + 0) * (ROWS_PB * WDIM);
    size_t base1 = (size_t)(blockIdx.x * TILES_PB + 1) * (ROWS_PB * WDIM);

    // tile-0 global loads
    int pa0 = sdist4[base0 / 4 + tid];
    int pa1 = sdist4[base0 / 4 + HTHREADS + tid];
    float4 xa0 = *(const float4*)(outp + base0 + tid * 4);
    float4 xa1 = *(const float4*)(outp + base0 + (size_t)(HTHREADS + tid) * 4);

    // pads once (constant across tiles; never overwritten)
    if (tid < ROWS_PB * 2 * PAD) {
        int r = tid / (2 * PAD);
        int c = tid % (2 * PAD);
        int off = r * LROW + (c < PAD ? c : WDIM + c);
        sf1[off] = 3.0e12f;
        sf0[off] = 3.0e12f;
    }

    // stage tile 0
    stage_write(sf1, sf0, pa0, tid);
    stage_write(sf1, sf0, pa1, HTHREADS + tid);
    __syncthreads();                        // B1: tile0 staged

    // issue tile-1 loads: latency hides under tile-0 scan
    int pb0 = sdist4[base1 / 4 + tid];
    int pb1 = sdist4[base1 / 4 + HTHREADS + tid];
    float4 xb0 = *(const float4*)(outp + base1 + tid * 4);
    float4 xb1 = *(const float4*)(outp + base1 + (size_t)(HTHREADS + tid) * 4);

    float local = 0.0f;
    local += scan_quad(sf1, sf0, tid * 4, xa0);
    local += scan_quad(sf1, sf0, (HTHREADS + tid) * 4, xa1);
    __syncthreads();                        // B2: all tile0 buf reads complete

    stage_write(sf1, sf0, pb0, tid);
    stage_write(sf1, sf0, pb1, HTHREADS + tid);
    __syncthreads();                        // B3: tile1 staged

    local += scan_quad(sf1, sf0, tid * 4, xb0);
    local += scan_quad(sf1, sf0, (HTHREADS + tid) * 4, xb1);

    // wave reduce fp32, then fp64 across waves
    float v = local;
    #pragma unroll
    for (int off = 32; off > 0; off >>= 1) v += __shfl_down(v, off, 64);
    int wid = tid >> 6, lane = tid & 63;
    if (lane == 0) swave[wid] = (double)v;
    __syncthreads();
    if (tid == 0) partial[blockIdx.x] = swave[0] + swave[1] + swave[2] + swave[3];
}

// ---------------- finalize: sum partials -> mean ----------------
__global__ __launch_bounds__(256) void finalize20(const double* __restrict__ partial,
                                                  float* __restrict__ out,
                                                  int npart, double invN) {
    __shared__ double swave[4];
    int tid = threadIdx.x;
    double local = 0.0;
    for (int i = tid; i < npart; i += 256) local += partial[i];
    #pragma unroll
    for (int off = 32; off > 0; off >>= 1) local += __shfl_down(local, off, 64);
    int wid = tid >> 6, lane = tid & 63;
    if (lane == 0) swave[wid] = local;
    __syncthreads();
    if (tid == 0) out[0] = (float)((swave[0] + swave[1] + swave[2] + swave[3]) * invN);
}

extern "C" void kernel_launch(void* const* d_in, const int* in_sizes, int n_in,
                              void* d_out, int out_size, void* d_ws, size_t ws_size,
                              hipStream_t stream) {
    const float* outp = (const float*)d_in[0];
    const int* tgt = (const int*)d_in[1];
    int N = in_sizes[0];                    // B*C*H*W
    int B = N / (HDIM * WDIM);              // 16

    int npart = (B * HDIM) / (ROWS_PB * TILES_PB);   // 1024

    double* partial = (double*)((char*)d_ws + 256);
    signed char* sdist = (signed char*)((char*)d_ws + 32768);

    vert_pass20<<<B * (WDIM / VCOLS), VTHREADS, 0, stream>>>(tgt, sdist);
    horiz_pass20<<<npart, HTHREADS, 0, stream>>>((const int*)sdist, outp, partial);
    finalize20<<<1, 256, 0, stream>>>(partial, (float*)d_out, npart, 1.0 / (double)N);
}